// Round 9
// baseline (5515.639 us; speedup 1.0000x reference)
//
#include <hip/hip_runtime.h>
#include <hip/hip_bf16.h>

// GRU: V=50000, E=256, H=256, B=64, T=512
// out: outputs[T,B,H] f32 then h_last[1,B,H] f32 (concat flat)

#define T_SEQ 512
#define B_SZ 64
#define E_DIM 256
#define H_DIM 256
#define G3 768   // 3*H

typedef _Float16 half2v __attribute__((ext_vector_type(2)));
typedef _Float16 f16x8  __attribute__((ext_vector_type(8)));
typedef float    f32x4  __attribute__((ext_vector_type(4)));

#if __has_builtin(__builtin_amdgcn_fdot2)
#define FDOT2(a, b, c) __builtin_amdgcn_fdot2((a), (b), (c), false)
#else
#define FDOT2(a, b, c) ((c) + (float)(a).x * (float)(b).x + (float)(a).y * (float)(b).y)
#endif

// ---------------- Kernel 0: W_hh f32 -> f16 (once) -------------------------
__global__ __launch_bounds__(256) void convert_whh(
    const float* __restrict__ W, _Float16* __restrict__ wf)
{
    int i = blockIdx.x * 256 + threadIdx.x;   // 49152 threads, 4 elems each
    float4 v = reinterpret_cast<const float4*>(W)[i];
    half2v a{(_Float16)v.x, (_Float16)v.y};
    half2v b{(_Float16)v.z, (_Float16)v.w};
    uint2 o{__builtin_bit_cast(uint32_t, a), __builtin_bit_cast(uint32_t, b)};
    reinterpret_cast<uint2*>(wf)[i] = o;
}

// ---------------- Kernel A: x_proj via MFMA f16 (working since R6) ---------
__global__ __launch_bounds__(256) void xproj_mfma_kernel(
    const int* __restrict__ input,
    const float* __restrict__ emb,
    const float* __restrict__ W_ih,
    const float* __restrict__ b_ih,
    const float* __restrict__ b_hh,
    _Float16* __restrict__ xp)
{
    __shared__ int rowidx[128];
    __shared__ __align__(16) _Float16 Af[2][128][40];
    __shared__ __align__(16) _Float16 Bf[2][128][40];

    const int tid = threadIdx.x;
    const int m0 = blockIdx.x * 128;
    const int n0 = blockIdx.y * 128;
    const int w  = tid >> 6;
    const int l  = tid & 63;
    const int g  = l >> 4;
    const int lr = l & 15;

    if (tid < 128) {
        int m = m0 + tid;
        rowidx[tid] = input[(m & 63) * T_SEQ + (m >> 6)];
    }
    __syncthreads();

    const int srow = tid >> 1;
    const int sseg = tid & 1;

    {
        const float* sa = emb + (size_t)rowidx[srow] * E_DIM + sseg * 16;
        const float* sb = W_ih + (size_t)(n0 + srow) * E_DIM + sseg * 16;
        float4 av0 = reinterpret_cast<const float4*>(sa)[0];
        float4 av1 = reinterpret_cast<const float4*>(sa)[1];
        float4 av2 = reinterpret_cast<const float4*>(sa)[2];
        float4 av3 = reinterpret_cast<const float4*>(sa)[3];
        float4 bv0 = reinterpret_cast<const float4*>(sb)[0];
        float4 bv1 = reinterpret_cast<const float4*>(sb)[1];
        float4 bv2 = reinterpret_cast<const float4*>(sb)[2];
        float4 bv3 = reinterpret_cast<const float4*>(sb)[3];
        _Float16* da = &Af[0][srow][sseg * 16];
        _Float16* db = &Bf[0][srow][sseg * 16];
        #pragma unroll
        for (int u = 0; u < 4; ++u) {
            float4 a = (u==0)?av0:(u==1)?av1:(u==2)?av2:av3;
            float4 bq = (u==0)?bv0:(u==1)?bv1:(u==2)?bv2:bv3;
            da[u*4+0]=(_Float16)a.x; da[u*4+1]=(_Float16)a.y;
            da[u*4+2]=(_Float16)a.z; da[u*4+3]=(_Float16)a.w;
            db[u*4+0]=(_Float16)bq.x; db[u*4+1]=(_Float16)bq.y;
            db[u*4+2]=(_Float16)bq.z; db[u*4+3]=(_Float16)bq.w;
        }
    }
    __syncthreads();

    f32x4 acc[2][8];
    #pragma unroll
    for (int mt = 0; mt < 2; ++mt)
        #pragma unroll
        for (int nt = 0; nt < 8; ++nt)
            acc[mt][nt] = f32x4{0.f, 0.f, 0.f, 0.f};

    int p = 0;
    for (int kk = 0; kk < 8; ++kk) {
        float4 av0, av1, av2, av3, bv0, bv1, bv2, bv3;
        if (kk < 7) {
            const float* sa = emb + (size_t)rowidx[srow] * E_DIM + (kk+1)*32 + sseg*16;
            const float* sb = W_ih + (size_t)(n0 + srow) * E_DIM + (kk+1)*32 + sseg*16;
            av0 = reinterpret_cast<const float4*>(sa)[0];
            av1 = reinterpret_cast<const float4*>(sa)[1];
            av2 = reinterpret_cast<const float4*>(sa)[2];
            av3 = reinterpret_cast<const float4*>(sa)[3];
            bv0 = reinterpret_cast<const float4*>(sb)[0];
            bv1 = reinterpret_cast<const float4*>(sb)[1];
            bv2 = reinterpret_cast<const float4*>(sb)[2];
            bv3 = reinterpret_cast<const float4*>(sb)[3];
        }

        f16x8 afr[2], bfr[8];
        #pragma unroll
        for (int mt = 0; mt < 2; ++mt) {
            uint4 u = *reinterpret_cast<const uint4*>(&Af[p][w*32 + mt*16 + lr][g*8]);
            afr[mt] = __builtin_bit_cast(f16x8, u);
        }
        #pragma unroll
        for (int nt = 0; nt < 8; ++nt) {
            uint4 u = *reinterpret_cast<const uint4*>(&Bf[p][nt*16 + lr][g*8]);
            bfr[nt] = __builtin_bit_cast(f16x8, u);
        }
        #pragma unroll
        for (int mt = 0; mt < 2; ++mt)
            #pragma unroll
            for (int nt = 0; nt < 8; ++nt)
                acc[mt][nt] = __builtin_amdgcn_mfma_f32_16x16x32_f16(
                    afr[mt], bfr[nt], acc[mt][nt], 0, 0, 0);

        if (kk < 7) {
            _Float16* da = &Af[p ^ 1][srow][sseg * 16];
            _Float16* db = &Bf[p ^ 1][srow][sseg * 16];
            #pragma unroll
            for (int u = 0; u < 4; ++u) {
                float4 a = (u==0)?av0:(u==1)?av1:(u==2)?av2:av3;
                float4 bq = (u==0)?bv0:(u==1)?bv1:(u==2)?bv2:bv3;
                da[u*4+0]=(_Float16)a.x; da[u*4+1]=(_Float16)a.y;
                da[u*4+2]=(_Float16)a.z; da[u*4+3]=(_Float16)a.w;
                db[u*4+0]=(_Float16)bq.x; db[u*4+1]=(_Float16)bq.y;
                db[u*4+2]=(_Float16)bq.z; db[u*4+3]=(_Float16)bq.w;
            }
        }
        __syncthreads();
        p ^= 1;
    }

    #pragma unroll
    for (int nt = 0; nt < 8; ++nt) {
        const int col = n0 + nt * 16 + lr;
        const float bias = b_ih[col] + (col < 512 ? b_hh[col] : 0.0f);
        #pragma unroll
        for (int mt = 0; mt < 2; ++mt) {
            const int rbase = m0 + w * 32 + mt * 16 + g * 4;
            #pragma unroll
            for (int i = 0; i < 4; ++i)
                xp[(size_t)(rbase + i) * G3 + col] = (_Float16)(acc[mt][nt][i] + bias);
        }
    }
}

// ---------------- Kernel B: GRU scan, clean f16 weight streaming -----------
// 64 blocks (1/batch), 512 threads = 8 waves, launch_bounds(512,2): the
// allocator's proven-stable 128-VGPR operating point (R2-R5). Design rules
// from R2-R7 failures: NO arrays (rule #20 scratch), named pointers re-pinned
// via empty asm each iteration (blocks LICM from hoisting 48 loads into a
// spilling live set), h staged in 8 named regs via rotated-chunk ds_read_b128
// (R2-verified (c+2q)&7 -> 0 bank conflicts), weight rows streamed as
// contiguous 128B L2 lines per lane with the rotation applied as a LOAD-SLOT
// permutation (all register indices compile-time).
// Mem floor: 393KB f16/block-step @ ~4.7TB/s/XCD (measured) -> ~340ns/step.
__device__ __forceinline__ float fast_sigmoid(float x) {
    float e = __expf(-x);
    return __builtin_amdgcn_rcpf(1.0f + e);
}
__device__ __forceinline__ float fast_tanh(float x) {
    x = fminf(x, 8.0f);
    float e = __expf(2.0f * x);
    return (e - 1.0f) * __builtin_amdgcn_rcpf(e + 1.0f);
}

#define B2(u) __builtin_bit_cast(half2v, u)
// one 16B chunk (8 halves) of row against matching h chunk: 4 dot2
#define CH(ACC, L, HV)                                   \
    ACC = FDOT2(B2(L.x), B2(HV.x), ACC);                 \
    ACC = FDOT2(B2(L.y), B2(HV.y), ACC);                 \
    ACC = FDOT2(B2(L.z), B2(HV.z), ACC);                 \
    ACC = FDOT2(B2(L.w), B2(HV.w), ACC);
// one full row slice (8 chunks, rotated slot order matches hv slots)
#define DOTROW(P, ACC)                                                   \
    {                                                                    \
        uint4 l0 = P[k0], l1 = P[k1], l2 = P[k2], l3 = P[k3];            \
        uint4 l4 = P[k4], l5 = P[k5], l6 = P[k6], l7 = P[k7];            \
        CH(ACC, l0, hv0) CH(ACC, l1, hv1) CH(ACC, l2, hv2)               \
        CH(ACC, l3, hv3) CH(ACC, l4, hv4) CH(ACC, l5, hv5)               \
        CH(ACC, l6, hv6) CH(ACC, l7, hv7)                                \
    }

__global__ __launch_bounds__(512, 2) void gru_scan_kernel(
    const _Float16* __restrict__ xp,   // [T*B, 768] f16 (b_ih + r/z b_hh folded)
    const _Float16* __restrict__ wf,   // [768, 256] f16
    const float* __restrict__ b_hh,
    float* __restrict__ out)           // outputs [T*B*256] ++ h_last [64*256]
{
    const int b   = blockIdx.x;
    const int tid = threadIdx.x;
    const int jj  = tid >> 2;      // 0..127 : columns (jj, jj+128)
    const int q   = tid & 3;       // k-slice [64q, 64q+64)

    __shared__ __align__(16) _Float16 hs[2][H_DIM];

    // rotated chunk slots (runtime q folds into address math only)
    const int k0 = ((0 + 2*q) & 7), k1 = ((1 + 2*q) & 7);
    const int k2 = ((2 + 2*q) & 7), k3 = ((3 + 2*q) & 7);
    const int k4 = ((4 + 2*q) & 7), k5 = ((5 + 2*q) & 7);
    const int k6 = ((6 + 2*q) & 7), k7 = ((7 + 2*q) & 7);

    // 6 stream pointers, one per owned W_hh row, offset to this k-slice
    uintptr_t P0 = (uintptr_t)(wf + (size_t)(jj +   0) * H_DIM + q * 64);
    uintptr_t P1 = (uintptr_t)(wf + (size_t)(jj + 128) * H_DIM + q * 64);
    uintptr_t P2 = (uintptr_t)(wf + (size_t)(jj + 256) * H_DIM + q * 64);
    uintptr_t P3 = (uintptr_t)(wf + (size_t)(jj + 384) * H_DIM + q * 64);
    uintptr_t P4 = (uintptr_t)(wf + (size_t)(jj + 512) * H_DIM + q * 64);
    uintptr_t P5 = (uintptr_t)(wf + (size_t)(jj + 640) * H_DIM + q * 64);

    const float bn0 = b_hh[512 + jj];
    const float bn1 = b_hh[512 + jj + 128];

    if (tid < 32) reinterpret_cast<uint4*>(hs[0])[tid] = uint4{0, 0, 0, 0};
    __syncthreads();

    const int c0 = jj, c1 = jj + 128;
    float h0 = 0.0f, h1 = 0.0f;

    for (int t = 0; t < T_SEQ; ++t) {
        // opaque re-pin: addresses become loop-variant -> loads stay in-loop
        asm volatile("" : "+v"(P0), "+v"(P1), "+v"(P2),
                          "+v"(P3), "+v"(P4), "+v"(P5));
        const uint4* p0 = (const uint4*)P0;
        const uint4* p1 = (const uint4*)P1;
        const uint4* p2 = (const uint4*)P2;
        const uint4* p3 = (const uint4*)P3;
        const uint4* p4 = (const uint4*)P4;
        const uint4* p5 = (const uint4*)P5;

        const _Float16* xrow = xp + ((size_t)t * B_SZ + b) * G3;
        const float xr0 = (float)xrow[c0],       xr1 = (float)xrow[c1];
        const float xz0 = (float)xrow[256 + c0], xz1 = (float)xrow[256 + c1];
        const float xn0 = (float)xrow[512 + c0], xn1 = (float)xrow[512 + c1];

        // h slice (64 halves) -> 8 named regs, rotated order (bank-free)
        const char* hb = reinterpret_cast<const char*>(&hs[t & 1][0]) + q * 128;
        const uint4 hv0 = *reinterpret_cast<const uint4*>(hb + k0 * 16);
        const uint4 hv1 = *reinterpret_cast<const uint4*>(hb + k1 * 16);
        const uint4 hv2 = *reinterpret_cast<const uint4*>(hb + k2 * 16);
        const uint4 hv3 = *reinterpret_cast<const uint4*>(hb + k3 * 16);
        const uint4 hv4 = *reinterpret_cast<const uint4*>(hb + k4 * 16);
        const uint4 hv5 = *reinterpret_cast<const uint4*>(hb + k5 * 16);
        const uint4 hv6 = *reinterpret_cast<const uint4*>(hb + k6 * 16);
        const uint4 hv7 = *reinterpret_cast<const uint4*>(hb + k7 * 16);

        float a0 = 0.f, a1 = 0.f, a2 = 0.f, a3 = 0.f, a4 = 0.f, a5 = 0.f;
        DOTROW(p0, a0)
        DOTROW(p1, a1)
        DOTROW(p2, a2)
        DOTROW(p3, a3)
        DOTROW(p4, a4)
        DOTROW(p5, a5)

        // quad butterfly reduce
        a0 += __shfl_xor(a0, 1); a0 += __shfl_xor(a0, 2);
        a1 += __shfl_xor(a1, 1); a1 += __shfl_xor(a1, 2);
        a2 += __shfl_xor(a2, 1); a2 += __shfl_xor(a2, 2);
        a3 += __shfl_xor(a3, 1); a3 += __shfl_xor(a3, 2);
        a4 += __shfl_xor(a4, 1); a4 += __shfl_xor(a4, 2);
        a5 += __shfl_xor(a5, 1); a5 += __shfl_xor(a5, 2);

        const float r0 = fast_sigmoid(xr0 + a0);
        const float r1 = fast_sigmoid(xr1 + a1);
        const float z0 = fast_sigmoid(xz0 + a2);
        const float z1 = fast_sigmoid(xz1 + a3);
        const float n0 = fast_tanh(xn0 + r0 * (a4 + bn0));
        const float n1 = fast_tanh(xn1 + r1 * (a5 + bn1));
        h0 = (1.0f - z0) * n0 + z0 * h0;
        h1 = (1.0f - z1) * n1 + z1 * h1;

        if (q == 0) {
            float* orow = out + ((size_t)t * B_SZ + b) * H_DIM;
            orow[c0] = h0;
            orow[c1] = h1;
            hs[(t + 1) & 1][c0] = (_Float16)h0;
            hs[(t + 1) & 1][c1] = (_Float16)h1;
        }
        __syncthreads();
    }

    if (q == 0) {
        float* hl = out + (size_t)T_SEQ * B_SZ * H_DIM + (size_t)b * H_DIM;
        hl[c0] = h0;
        hl[c1] = h1;
    }
}

extern "C" void kernel_launch(void* const* d_in, const int* in_sizes, int n_in,
                              void* d_out, int out_size, void* d_ws, size_t ws_size,
                              hipStream_t stream) {
    const int*   input = (const int*)d_in[0];
    const float* emb   = (const float*)d_in[1];
    const float* W_ih  = (const float*)d_in[2];
    const float* W_hh  = (const float*)d_in[3];
    const float* b_ih  = (const float*)d_in[4];
    const float* b_hh  = (const float*)d_in[5];
    float* out = (float*)d_out;

    _Float16* xp   = (_Float16*)d_ws;                       // 50,331,648 B
    _Float16* wf16 = (_Float16*)((char*)d_ws + 50331648);   // 393,216 B

    convert_whh<<<192, 256, 0, stream>>>(W_hh, wf16);

    dim3 gridA(T_SEQ * B_SZ / 128, G3 / 128);   // (256, 6)
    xproj_mfma_kernel<<<gridA, 256, 0, stream>>>(input, emb, W_ih, b_ih, b_hh, xp);

    gru_scan_kernel<<<B_SZ, 512, 0, stream>>>(xp, wf16, b_hh, out);
}

// Round 10
// 1653.930 us; speedup vs baseline: 3.3349x; 3.3349x over previous
//
#include <hip/hip_runtime.h>
#include <hip/hip_bf16.h>

// GRU: V=50000, E=256, H=256, B=64, T=512
// out: outputs[T,B,H] f32 then h_last[1,B,H] f32 (concat flat)

#define T_SEQ 512
#define B_SZ 64
#define E_DIM 256
#define H_DIM 256
#define G3 768   // 3*H

typedef _Float16 half2v __attribute__((ext_vector_type(2)));
typedef _Float16 f16x8  __attribute__((ext_vector_type(8)));
typedef float    f32x4  __attribute__((ext_vector_type(4)));

// ---------------- Kernel 0: W_hh f32 -> f16 (once) -------------------------
__global__ __launch_bounds__(256) void convert_whh(
    const float* __restrict__ W, _Float16* __restrict__ wf)
{
    int i = blockIdx.x * 256 + threadIdx.x;   // 49152 threads, 4 elems each
    float4 v = reinterpret_cast<const float4*>(W)[i];
    half2v a{(_Float16)v.x, (_Float16)v.y};
    half2v b{(_Float16)v.z, (_Float16)v.w};
    uint2 o{__builtin_bit_cast(uint32_t, a), __builtin_bit_cast(uint32_t, b)};
    reinterpret_cast<uint2*>(wf)[i] = o;
}

// ---------------- Kernel A: x_proj via MFMA f16 (working since R6) ---------
__global__ __launch_bounds__(256) void xproj_mfma_kernel(
    const int* __restrict__ input,
    const float* __restrict__ emb,
    const float* __restrict__ W_ih,
    const float* __restrict__ b_ih,
    const float* __restrict__ b_hh,
    _Float16* __restrict__ xp)
{
    __shared__ int rowidx[128];
    __shared__ __align__(16) _Float16 Af[2][128][40];
    __shared__ __align__(16) _Float16 Bf[2][128][40];

    const int tid = threadIdx.x;
    const int m0 = blockIdx.x * 128;
    const int n0 = blockIdx.y * 128;
    const int w  = tid >> 6;
    const int l  = tid & 63;
    const int g  = l >> 4;
    const int lr = l & 15;

    if (tid < 128) {
        int m = m0 + tid;
        rowidx[tid] = input[(m & 63) * T_SEQ + (m >> 6)];
    }
    __syncthreads();

    const int srow = tid >> 1;
    const int sseg = tid & 1;

    {
        const float* sa = emb + (size_t)rowidx[srow] * E_DIM + sseg * 16;
        const float* sb = W_ih + (size_t)(n0 + srow) * E_DIM + sseg * 16;
        float4 av0 = reinterpret_cast<const float4*>(sa)[0];
        float4 av1 = reinterpret_cast<const float4*>(sa)[1];
        float4 av2 = reinterpret_cast<const float4*>(sa)[2];
        float4 av3 = reinterpret_cast<const float4*>(sa)[3];
        float4 bv0 = reinterpret_cast<const float4*>(sb)[0];
        float4 bv1 = reinterpret_cast<const float4*>(sb)[1];
        float4 bv2 = reinterpret_cast<const float4*>(sb)[2];
        float4 bv3 = reinterpret_cast<const float4*>(sb)[3];
        _Float16* da = &Af[0][srow][sseg * 16];
        _Float16* db = &Bf[0][srow][sseg * 16];
        #pragma unroll
        for (int u = 0; u < 4; ++u) {
            float4 a = (u==0)?av0:(u==1)?av1:(u==2)?av2:av3;
            float4 bq = (u==0)?bv0:(u==1)?bv1:(u==2)?bv2:bv3;
            da[u*4+0]=(_Float16)a.x; da[u*4+1]=(_Float16)a.y;
            da[u*4+2]=(_Float16)a.z; da[u*4+3]=(_Float16)a.w;
            db[u*4+0]=(_Float16)bq.x; db[u*4+1]=(_Float16)bq.y;
            db[u*4+2]=(_Float16)bq.z; db[u*4+3]=(_Float16)bq.w;
        }
    }
    __syncthreads();

    f32x4 acc[2][8];
    #pragma unroll
    for (int mt = 0; mt < 2; ++mt)
        #pragma unroll
        for (int nt = 0; nt < 8; ++nt)
            acc[mt][nt] = f32x4{0.f, 0.f, 0.f, 0.f};

    int p = 0;
    for (int kk = 0; kk < 8; ++kk) {
        float4 av0, av1, av2, av3, bv0, bv1, bv2, bv3;
        if (kk < 7) {
            const float* sa = emb + (size_t)rowidx[srow] * E_DIM + (kk+1)*32 + sseg*16;
            const float* sb = W_ih + (size_t)(n0 + srow) * E_DIM + (kk+1)*32 + sseg*16;
            av0 = reinterpret_cast<const float4*>(sa)[0];
            av1 = reinterpret_cast<const float4*>(sa)[1];
            av2 = reinterpret_cast<const float4*>(sa)[2];
            av3 = reinterpret_cast<const float4*>(sa)[3];
            bv0 = reinterpret_cast<const float4*>(sb)[0];
            bv1 = reinterpret_cast<const float4*>(sb)[1];
            bv2 = reinterpret_cast<const float4*>(sb)[2];
            bv3 = reinterpret_cast<const float4*>(sb)[3];
        }

        f16x8 afr[2], bfr[8];
        #pragma unroll
        for (int mt = 0; mt < 2; ++mt) {
            uint4 u = *reinterpret_cast<const uint4*>(&Af[p][w*32 + mt*16 + lr][g*8]);
            afr[mt] = __builtin_bit_cast(f16x8, u);
        }
        #pragma unroll
        for (int nt = 0; nt < 8; ++nt) {
            uint4 u = *reinterpret_cast<const uint4*>(&Bf[p][nt*16 + lr][g*8]);
            bfr[nt] = __builtin_bit_cast(f16x8, u);
        }
        #pragma unroll
        for (int mt = 0; mt < 2; ++mt)
            #pragma unroll
            for (int nt = 0; nt < 8; ++nt)
                acc[mt][nt] = __builtin_amdgcn_mfma_f32_16x16x32_f16(
                    afr[mt], bfr[nt], acc[mt][nt], 0, 0, 0);

        if (kk < 7) {
            _Float16* da = &Af[p ^ 1][srow][sseg * 16];
            _Float16* db = &Bf[p ^ 1][srow][sseg * 16];
            #pragma unroll
            for (int u = 0; u < 4; ++u) {
                float4 a = (u==0)?av0:(u==1)?av1:(u==2)?av2:av3;
                float4 bq = (u==0)?bv0:(u==1)?bv1:(u==2)?bv2:bv3;
                da[u*4+0]=(_Float16)a.x; da[u*4+1]=(_Float16)a.y;
                da[u*4+2]=(_Float16)a.z; da[u*4+3]=(_Float16)a.w;
                db[u*4+0]=(_Float16)bq.x; db[u*4+1]=(_Float16)bq.y;
                db[u*4+2]=(_Float16)bq.z; db[u*4+3]=(_Float16)bq.w;
            }
        }
        __syncthreads();
        p ^= 1;
    }

    #pragma unroll
    for (int nt = 0; nt < 8; ++nt) {
        const int col = n0 + nt * 16 + lr;
        const float bias = b_ih[col] + (col < 512 ? b_hh[col] : 0.0f);
        #pragma unroll
        for (int mt = 0; mt < 2; ++mt) {
            const int rbase = m0 + w * 32 + mt * 16 + g * 4;
            #pragma unroll
            for (int i = 0; i < 4; ++i)
                xp[(size_t)(rbase + i) * G3 + col] = (_Float16)(acc[mt][nt][i] + bias);
        }
    }
}

// ---------------- Kernel B: GRU scan as MFMA, weights AGPR-resident --------
// 4 blocks x 512 threads (8 waves, 2/SIMD). Block bg owns batches
// [16bg, 16bg+16). Per step: hp[768,16] = W_hh @ h -- 48 M-tiles x 8 K of
// mfma_f32_16x16x32_f16. Wave w owns M-tiles {2w,2w+1,16+2w,17+2w,32+2w,
// 33+2w} so r/z/n of column j=32w..32w+31 stay in-lane (gates in-register,
// h_prev in-register). Weights: 48 f16x8 frags/thread = 192 AGPRs, loaded
// once, pinned "+a" (R7: compiles), consumed by asm MFMA "a" operand (ISA
// allows A from AGPR -- this is what v_dot2 could not do). Zero weight
// traffic in the t-loop. h in LDS [16][264] f16 (pad: batch-stride aliases
// only 2-way = free). One barrier/step (double-buffered h).
__device__ __forceinline__ float fast_sigmoid(float x) {
    float e = __expf(-x);
    return __builtin_amdgcn_rcpf(1.0f + e);
}
__device__ __forceinline__ float fast_tanh(float x) {
    x = fminf(x, 8.0f);
    float e = __expf(2.0f * x);
    return (e - 1.0f) * __builtin_amdgcn_rcpf(e + 1.0f);
}

#define HROW 264   // padded h row stride (halves)

#define MFMA_A(ACC, AW, BH) \
    asm("v_mfma_f32_16x16x32_f16 %0, %1, %2, %0" : "+v"(ACC) : "a"(AW), "v"(BH))

// load 8 K-fragments of one M-tile into pinned AGPR vars
#define LOADW(S, MT) { \
    const _Float16* wr_ = wf + (size_t)((MT)*16 + lr) * H_DIM + kg*8; \
    A##S##0 = *(const f16x8*)(wr_ + 0*32); \
    A##S##1 = *(const f16x8*)(wr_ + 1*32); \
    A##S##2 = *(const f16x8*)(wr_ + 2*32); \
    A##S##3 = *(const f16x8*)(wr_ + 3*32); \
    A##S##4 = *(const f16x8*)(wr_ + 4*32); \
    A##S##5 = *(const f16x8*)(wr_ + 5*32); \
    A##S##6 = *(const f16x8*)(wr_ + 6*32); \
    A##S##7 = *(const f16x8*)(wr_ + 7*32); \
    asm volatile("" : "+a"(A##S##0), "+a"(A##S##1), "+a"(A##S##2), "+a"(A##S##3), \
                      "+a"(A##S##4), "+a"(A##S##5), "+a"(A##S##6), "+a"(A##S##7)); \
}

#define KSTEP(KS) { \
    f16x8 bh_ = *(const f16x8*)(hrow + (KS)*32); \
    MFMA_A(ar0, A0##KS, bh_); \
    MFMA_A(ar1, A1##KS, bh_); \
    MFMA_A(az0, A2##KS, bh_); \
    MFMA_A(az1, A3##KS, bh_); \
    MFMA_A(an0, A4##KS, bh_); \
    MFMA_A(an1, A5##KS, bh_); \
}

// extract f16 element I (0..3) of a uint2 as float (compile-time I)
#define XF(U, I) ((I) < 2 ? (float)__builtin_bit_cast(half2v, (U).x)[(I)] \
                          : (float)__builtin_bit_cast(half2v, (U).y)[(I)-2])

__global__ __launch_bounds__(512, 2) void gru_mfma_scan(
    const _Float16* __restrict__ xp,   // [T*B, 768] f16 (b_ih + r/z b_hh folded)
    const _Float16* __restrict__ wf,   // [768, 256] f16
    const float* __restrict__ b_hh,
    float* __restrict__ out)           // outputs [T*B*256] ++ h_last [64*256]
{
    const int bg  = blockIdx.x;        // batch group 0..3
    const int tid = threadIdx.x;
    const int w   = tid >> 6;          // wave 0..7
    const int l   = tid & 63;
    const int lr  = l & 15;            // A row-in-tile / B,D col (= batch)
    const int kg  = l >> 4;            // k-group 0..3 (also D row-group)
    const int batch = lr;
    const int jbase = 32 * w + kg * 4; // first output column of this lane

    __shared__ __align__(16) _Float16 hs[2][16][HROW];

    // ---- weights -> AGPRs (once) ----
    f16x8 A00,A01,A02,A03,A04,A05,A06,A07;
    f16x8 A10,A11,A12,A13,A14,A15,A16,A17;
    f16x8 A20,A21,A22,A23,A24,A25,A26,A27;
    f16x8 A30,A31,A32,A33,A34,A35,A36,A37;
    f16x8 A40,A41,A42,A43,A44,A45,A46,A47;
    f16x8 A50,A51,A52,A53,A54,A55,A56,A57;
    LOADW(0, 2*w)        // r gate, tile 0
    LOADW(1, 2*w + 1)    // r gate, tile 1
    LOADW(2, 16 + 2*w)   // z gate, tile 0
    LOADW(3, 17 + 2*w)   // z gate, tile 1
    LOADW(4, 32 + 2*w)   // n gate, tile 0
    LOADW(5, 33 + 2*w)   // n gate, tile 1

    // n-gate b_hh for this lane's 8 columns (loop-invariant)
    const float4 bnv0 = *reinterpret_cast<const float4*>(b_hh + 512 + jbase);
    const float4 bnv1 = *reinterpret_cast<const float4*>(b_hh + 512 + jbase + 16);

    // zero h buffer 0
    {
        uint32_t* z = reinterpret_cast<uint32_t*>(&hs[0][0][0]);
        for (int i = tid; i < 16 * HROW / 2; i += 512) z[i] = 0u;
    }
    __syncthreads();

    float4 hp0 = {0.f, 0.f, 0.f, 0.f};   // previous h, cols jbase+0..3
    float4 hp1 = {0.f, 0.f, 0.f, 0.f};   // previous h, cols jbase+16..19

    const int gb = bg * 16 + batch;      // global batch index

    for (int t = 0; t < T_SEQ; ++t) {
        // xp loads issued first, consumed after MFMA phase
        const _Float16* xrow = xp + ((size_t)t * B_SZ + gb) * G3;
        const uint2 xr0 = *reinterpret_cast<const uint2*>(xrow + jbase);
        const uint2 xr1 = *reinterpret_cast<const uint2*>(xrow + jbase + 16);
        const uint2 xz0 = *reinterpret_cast<const uint2*>(xrow + 256 + jbase);
        const uint2 xz1 = *reinterpret_cast<const uint2*>(xrow + 256 + jbase + 16);
        const uint2 xn0 = *reinterpret_cast<const uint2*>(xrow + 512 + jbase);
        const uint2 xn1 = *reinterpret_cast<const uint2*>(xrow + 512 + jbase + 16);

        f32x4 ar0 = {0.f,0.f,0.f,0.f}, ar1 = {0.f,0.f,0.f,0.f};
        f32x4 az0 = {0.f,0.f,0.f,0.f}, az1 = {0.f,0.f,0.f,0.f};
        f32x4 an0 = {0.f,0.f,0.f,0.f}, an1 = {0.f,0.f,0.f,0.f};

        const _Float16* hrow = &hs[t & 1][batch][kg * 8];
        KSTEP(0) KSTEP(1) KSTEP(2) KSTEP(3)
        KSTEP(4) KSTEP(5) KSTEP(6) KSTEP(7)

        // ---- gates (all in-register; D row i = jbase+i / jbase+16+i) ----
        float h0[4], h1[4];
        #pragma unroll
        for (int i = 0; i < 4; ++i) {
            const float r = fast_sigmoid(XF(xr0, i) + ar0[i]);
            const float z = fast_sigmoid(XF(xz0, i) + az0[i]);
            const float n = fast_tanh(XF(xn0, i) + r * (an0[i] + bnv0[i]));
            h0[i] = (1.0f - z) * n + z * hp0[i];
        }
        #pragma unroll
        for (int i = 0; i < 4; ++i) {
            const float r = fast_sigmoid(XF(xr1, i) + ar1[i]);
            const float z = fast_sigmoid(XF(xz1, i) + az1[i]);
            const float n = fast_tanh(XF(xn1, i) + r * (an1[i] + bnv1[i]));
            h1[i] = (1.0f - z) * n + z * hp1[i];
        }
        hp0 = float4{h0[0], h0[1], h0[2], h0[3]};
        hp1 = float4{h1[0], h1[1], h1[2], h1[3]};

        // store outputs (f32, 16B-aligned vector stores)
        float* orow = out + ((size_t)t * B_SZ + gb) * H_DIM;
        *reinterpret_cast<float4*>(orow + jbase)      = hp0;
        *reinterpret_cast<float4*>(orow + jbase + 16) = hp1;

        // write h_new (f16) for next step
        uint2 w0{__builtin_bit_cast(uint32_t, half2v{(_Float16)h0[0], (_Float16)h0[1]}),
                 __builtin_bit_cast(uint32_t, half2v{(_Float16)h0[2], (_Float16)h0[3]})};
        uint2 w1{__builtin_bit_cast(uint32_t, half2v{(_Float16)h1[0], (_Float16)h1[1]}),
                 __builtin_bit_cast(uint32_t, half2v{(_Float16)h1[2], (_Float16)h1[3]})};
        *reinterpret_cast<uint2*>(&hs[(t + 1) & 1][batch][jbase])      = w0;
        *reinterpret_cast<uint2*>(&hs[(t + 1) & 1][batch][jbase + 16]) = w1;

        __syncthreads();
    }

    // h_last
    float* hl = out + (size_t)T_SEQ * B_SZ * H_DIM + (size_t)gb * H_DIM;
    *reinterpret_cast<float4*>(hl + jbase)      = hp0;
    *reinterpret_cast<float4*>(hl + jbase + 16) = hp1;
}

extern "C" void kernel_launch(void* const* d_in, const int* in_sizes, int n_in,
                              void* d_out, int out_size, void* d_ws, size_t ws_size,
                              hipStream_t stream) {
    const int*   input = (const int*)d_in[0];
    const float* emb   = (const float*)d_in[1];
    const float* W_ih  = (const float*)d_in[2];
    const float* W_hh  = (const float*)d_in[3];
    const float* b_ih  = (const float*)d_in[4];
    const float* b_hh  = (const float*)d_in[5];
    float* out = (float*)d_out;

    _Float16* xp   = (_Float16*)d_ws;                       // 50,331,648 B
    _Float16* wf16 = (_Float16*)((char*)d_ws + 50331648);   // 393,216 B

    convert_whh<<<192, 256, 0, stream>>>(W_hh, wf16);

    dim3 gridA(T_SEQ * B_SZ / 128, G3 / 128);   // (256, 6)
    xproj_mfma_kernel<<<gridA, 256, 0, stream>>>(input, emb, W_ih, b_ih, b_hh, xp);

    gru_mfma_scan<<<4, 512, 0, stream>>>(xp, wf16, b_hh, out);
}